// Round 7
// baseline (228.892 us; speedup 1.0000x reference)
//
#include <hip/hip_runtime.h>

#define H     96    // hidden width of both MLPs
#define NOUT  32    // outputs of both MLPs
#define NSEG  97    // H+1 piecewise-linear segments
#define SENTR 97    // sentinel (all-zero) table row
#define NROW  98    // NSEG + sentinel
#define TPAD  128   // breakpoint array padded to pow2 for branchless search
#define TAB4  1568  // float4 per table: scalar float2[98][32], msg float4[98][16]

#define NPB_LOG 7
#define NPB     128   // nodes per bucket
#define MAXBK   800   // max buckets (N <= 102400)
#define EPB     8192  // edges per bucket_scatter block
#define CAP     3072  // max bucket size for fast finalize
#define NP      12    // CAP / 256 payloads staged per thread

// ---- d_ws float-index layout -------------------------------------------
#define WS_TS_MSG   0          // float[128] sorted breakpoints (+inf pad)
#define WS_TS_SC    128        // float[128]
#define WS_ACS      256        // float2[98][32]  scalar (A, C+b2) [s][k], row 97 = 0
#define WS_ACM      6528       // float4[98][16]  msg (A0,C0,A1,C1) [s][j], row 97 = 0
#define WS_RANK     12800      // int[192]
#define WS_GBH      16384      // int[800]  bucket sizes
#define WS_GBO      17184      // int[800]  bucket offsets (excl scan)
#define WS_GCUR     17984      // int[800]  bucket cursors
#define WS_OFFS     18784      // int[N+1]  CSR offsets
#define WS_PAY      118788     // float4[E] bucket-grouped payloads
// WS_PAY2 = WS_PAY + 4*E     // float4[E] node-sorted payloads (if ws allows)

// pk packing: bits 0..11 = sm*16, bits 12..23 = ss*32, bits 24..30 = col&127
#define SENT_PK ((SENTR << 4) | (SENTR << 17))

// ---------------------------------------------------------------------------
// P1: breakpoints t_j = -b1_j/w1_j, rank-sort, store sorted(+inf padded)+ranks
// ---------------------------------------------------------------------------
__global__ void build_breakpoints(const float* __restrict__ msg_w1,
                                  const float* __restrict__ msg_b1,
                                  const float* __restrict__ sc_w1,
                                  const float* __restrict__ sc_b1,
                                  float* __restrict__ ws) {
    __shared__ float t[2][H];
    const int tid = threadIdx.x;        // 192 threads
    const int mlp = tid / H;
    const int j   = tid % H;
    if (tid < 2 * H) {
        const float* w1 = mlp ? sc_w1 : msg_w1;
        const float* b1 = mlp ? sc_b1 : msg_b1;
        float w = w1[j], b = b1[j];
        t[mlp][j] = (w == 0.0f) ? __builtin_inff() : (-b / w);
    }
    __syncthreads();
    if (tid < 2 * H) {
        float tj = t[mlp][j];
        int r = 0;
        for (int i = 0; i < H; ++i) {
            float ti = t[mlp][i];
            r += (ti < tj) || (ti == tj && i < j);
        }
        float* ts = ws + (mlp ? WS_TS_SC : WS_TS_MSG);
        ts[r] = tj;
        ((int*)(ws + WS_RANK))[mlp * H + j] = r;
    }
    if (tid < 2 * (TPAD - H)) {
        int m2 = tid / (TPAD - H);
        int p  = tid % (TPAD - H);
        ws[m2 * TPAD + H + p] = __builtin_inff();
    }
}

// ---------------------------------------------------------------------------
// P2: per (segment, mlp): A,C with mlp(x) = A*x + C on that segment.
// s == 97 writes the all-zero sentinel row.
// ---------------------------------------------------------------------------
__global__ void build_tables(const float* __restrict__ msg_w1,
                             const float* __restrict__ msg_b1,
                             const float* __restrict__ msg_w2,
                             const float* __restrict__ msg_b2,
                             const float* __restrict__ sc_w1,
                             const float* __restrict__ sc_b1,
                             const float* __restrict__ sc_w2,
                             const float* __restrict__ sc_b2,
                             float* __restrict__ ws) {
    const int s   = blockIdx.x;   // 0..97
    const int mlp = blockIdx.y;   // 0 = msg, 1 = sc
    const int k   = threadIdx.x;  // 0..31
    float A = 0.0f, C = 0.0f;
    if (s != SENTR) {
        const float* w1 = mlp ? sc_w1 : msg_w1;
        const float* b1 = mlp ? sc_b1 : msg_b1;
        const float* w2 = mlp ? sc_w2 : msg_w2;
        const float* b2 = mlp ? sc_b2 : msg_b2;
        const int* rank = (const int*)(ws + WS_RANK) + mlp * H;
        for (int j = 0; j < H; ++j) {
            float w = w1[j], b = b1[j];
            int   r = rank[j];
            bool active = (w > 0.0f) ? (r < s)
                        : (w < 0.0f) ? (r >= s)
                                     : (b > 0.0f);
            if (active) {
                float wk = w2[j * NOUT + k];
                A = fmaf(w, wk, A);
                C = fmaf(b, wk, C);
            }
        }
        C += b2[k];
    }
    if (mlp) {
        float* dst = ws + WS_ACS + 2 * (s * 32 + k);
        dst[0] = A; dst[1] = C;
    } else {
        float* dst = ws + WS_ACM + 4 * (s * 16 + (k >> 1)) + 2 * (k & 1);
        dst[0] = A; dst[1] = C;
    }
}

// ---------------------------------------------------------------------------
// K1: bucket histogram (LDS-privatized)
// ---------------------------------------------------------------------------
__global__ __launch_bounds__(256) void bucket_hist(
    const int* __restrict__ col, int* __restrict__ gbh, int E, int NBK)
{
    __shared__ int lcnt[MAXBK];
    for (int i = threadIdx.x; i < MAXBK; i += 256) lcnt[i] = 0;
    __syncthreads();
    for (int e = blockIdx.x * 256 + threadIdx.x; e < E; e += gridDim.x * 256)
        atomicAdd(&lcnt[col[e] >> NPB_LOG], 1);
    __syncthreads();
    for (int i = threadIdx.x; i < NBK; i += 256)
        if (lcnt[i]) atomicAdd(&gbh[i], lcnt[i]);
}

// ---------------------------------------------------------------------------
// K2: exclusive scan of bucket sizes -> gbo, gcur (one block, 1024 threads)
// ---------------------------------------------------------------------------
__global__ void scan_buckets(const int* __restrict__ gbh,
                             int* __restrict__ gbo, int* __restrict__ gcur,
                             int NBK) {
    __shared__ int sh[1024];
    int t = threadIdx.x;
    int v = (t < NBK) ? gbh[t] : 0;
    sh[t] = v;
    __syncthreads();
    for (int off = 1; off < 1024; off <<= 1) {
        int u = (t >= off) ? sh[t - off] : 0;
        __syncthreads();
        sh[t] += u;
        __syncthreads();
    }
    if (t < NBK) { gbo[t] = sh[t] - v; gcur[t] = sh[t] - v; }
}

// ---------------------------------------------------------------------------
// K3: bucket scatter. payload = {x, sm*16 | (ss*32)<<12 | (col&127)<<24, c, s}
// ---------------------------------------------------------------------------
__global__ __launch_bounds__(256) void bucket_scatter(
    const float* __restrict__ v, const float* __restrict__ rot,
    const int* __restrict__ col, const float* __restrict__ ws,
    int* __restrict__ gcur, float4* __restrict__ pay, int E, int NBK)
{
    __shared__ float ts_m[TPAD], ts_s[TPAD];
    __shared__ int lcnt[MAXBK], lbase[MAXBK];
    for (int i = threadIdx.x; i < 2 * TPAD; i += 256) {
        float val = ws[i];
        if (i < TPAD) ts_m[i] = val; else ts_s[i - TPAD] = val;
    }
    for (int i = threadIdx.x; i < MAXBK; i += 256) lcnt[i] = 0;
    __syncthreads();
    const int e0 = blockIdx.x * EPB;
    const int e1 = min(e0 + EPB, E);
    for (int e = e0 + threadIdx.x; e < e1; e += 256)
        atomicAdd(&lcnt[col[e] >> NPB_LOG], 1);
    __syncthreads();
    for (int b = threadIdx.x; b < NBK; b += 256) {
        int c = lcnt[b];
        lbase[b] = c ? atomicAdd(&gcur[b], c) : 0;
        lcnt[b] = 0;                       // reuse as cursor
    }
    __syncthreads();
    for (int e = e0 + threadIdx.x; e < e1; e += 256) {
        int    c  = col[e];
        float2 vv = *(const float2*)(v + 2 * (size_t)e);
        float  x  = sqrtf(vv.x * vv.x + vv.y * vv.y);
        float4 r  = *(const float4*)(rot + 4 * (size_t)e);
        int sm = 0;
        #pragma unroll
        for (int st = 64; st > 0; st >>= 1) if (ts_m[sm + st - 1] < x) sm += st;
        int ss = 0;
        #pragma unroll
        for (int st = 64; st > 0; st >>= 1) if (ts_s[ss + st - 1] < x) ss += st;
        int b   = c >> NPB_LOG;
        int pos = lbase[b] + atomicAdd(&lcnt[b], 1);
        pay[pos] = make_float4(x,
            __int_as_float((sm << 4) | (ss << 17) | ((c & (NPB - 1)) << 24)),
            r.x, r.z);
    }
}

// ---------------------------------------------------------------------------
// K4: per-bucket finalize (col bits now 24..30; strip mask 0x00FFFFFF)
// ---------------------------------------------------------------------------
__global__ __launch_bounds__(256) void bucket_finalize(
    const float4* __restrict__ pay, float4* __restrict__ pay2,
    const int* __restrict__ gbh, const int* __restrict__ gbo,
    int* __restrict__ offs, int N, int NBK, int E)
{
    __shared__ float4 buf[CAP];                       // 48 KB
    __shared__ int s_cnt[NPB], s_scan[NPB], s_loff[NPB];
    const int b    = blockIdx.x;
    const int tid  = threadIdx.x;
    const int lo   = b << NPB_LOG;
    const int nn   = min(NPB, N - lo);
    const int bbeg = gbo[b];
    const int bsz  = gbh[b];
    if (tid < NPB) s_cnt[tid] = 0;
    __syncthreads();

    if (bsz <= CAP) {
        float4 p[NP];
        int    loc[NP];
        #pragma unroll
        for (int i = 0; i < NP; ++i) {
            int idx = i * 256 + tid;
            loc[i] = -1;
            if (idx < bsz) {
                p[i] = pay[bbeg + idx];
                loc[i] = (__float_as_int(p[i].y) >> 24) & 127;
                atomicAdd(&s_cnt[loc[i]], 1);
            }
        }
        __syncthreads();
        if (tid < NPB) s_scan[tid] = s_cnt[tid];
        __syncthreads();
        for (int off = 1; off < NPB; off <<= 1) {
            int u = (tid < NPB && tid >= off) ? s_scan[tid - off] : 0;
            __syncthreads();
            if (tid < NPB) s_scan[tid] += u;
            __syncthreads();
        }
        if (tid < NPB) s_loff[tid] = s_scan[tid] - s_cnt[tid];
        __syncthreads();
        if (tid < nn) offs[lo + tid] = bbeg + s_loff[tid];
        if (b == NBK - 1 && tid == 0) offs[N] = E;
        if (tid < NPB) s_cnt[tid] = 0;                // reuse as cursor
        __syncthreads();
        #pragma unroll
        for (int i = 0; i < NP; ++i) {
            if (loc[i] >= 0) {
                int pos = s_loff[loc[i]] + atomicAdd(&s_cnt[loc[i]], 1);
                float4 q = p[i];
                q.y = __int_as_float(__float_as_int(q.y) & 0x00FFFFFF);
                buf[pos] = q;
            }
        }
        __syncthreads();
        for (int idx = tid; idx < bsz; idx += 256)
            pay2[bbeg + idx] = buf[idx];
    } else {
        for (int idx = tid; idx < bsz; idx += 256) {
            int l = (__float_as_int(pay[bbeg + idx].y) >> 24) & 127;
            atomicAdd(&s_cnt[l], 1);
        }
        __syncthreads();
        if (tid < NPB) s_scan[tid] = s_cnt[tid];
        __syncthreads();
        for (int off = 1; off < NPB; off <<= 1) {
            int u = (tid < NPB && tid >= off) ? s_scan[tid - off] : 0;
            __syncthreads();
            if (tid < NPB) s_scan[tid] += u;
            __syncthreads();
        }
        if (tid < NPB) s_loff[tid] = s_scan[tid] - s_cnt[tid];
        __syncthreads();
        if (tid < nn) offs[lo + tid] = bbeg + s_loff[tid];
        if (b == NBK - 1 && tid == 0) offs[N] = E;
        if (tid < NPB) s_cnt[tid] = 0;
        __syncthreads();
        for (int idx = tid; idx < bsz; idx += 256) {
            float4 q = pay[bbeg + idx];
            int l = (__float_as_int(q.y) >> 24) & 127;
            int pos = s_loff[l] + atomicAdd(&s_cnt[l], 1);
            q.y = __int_as_float(__float_as_int(q.y) & 0x00FFFFFF);
            pay2[bbeg + pos] = q;
        }
    }
}

// ---------------------------------------------------------------------------
// Gather: fused dual-mode, wave = node, 32 outputs x 2 edge-slots.
// Sentinel row 97 (zeros) + sentinel payload slots -> guard-free inner loop,
// unroll x4 with 4 accumulator chains, pre-scaled pk indices.
// LDS = 25088 (table) + 4096 (paybuf) = 29184 B -> 5 blocks/CU.
// ---------------------------------------------------------------------------
__global__ __launch_bounds__(256) void gather_kernel(
    const float4* __restrict__ pay, const int* __restrict__ offs,
    const float* __restrict__ ws, float* __restrict__ out, int N)
{
    __shared__ float4 tabv[TAB4];         // 25088 B (incl sentinel row)
    __shared__ float4 paybuf[4][64];      //  4096 B
    const int mode = blockIdx.y;          // 0 = scalar, 1 = rot
    {
        const float4* src = (const float4*)(ws + (mode ? WS_ACM : WS_ACS));
        for (int i = threadIdx.x; i < TAB4; i += blockDim.x)
            tabv[i] = src[i];
    }
    __syncthreads();

    const int wv   = threadIdx.x >> 6;
    const int lane = threadIdx.x & 63;
    const int node = blockIdx.x * 4 + wv;
    if (node >= N) return;
    const int beg = offs[node], end = offs[node + 1];
    const int k    = lane & 31;
    const int half = lane >> 5;
    float4* pb = paybuf[wv];

    const float4 SENT = make_float4(0.f, __int_as_float(SENT_PK), 0.f, 0.f);
    float acc0 = 0.f, acc1 = 0.f, acc2 = 0.f, acc3 = 0.f;

    if (mode == 0) {
        const float2* t2 = (const float2*)tabv;
        for (int base = beg; base < end; base += 64) {
            int cnt = min(end - base, 64);
            pb[lane] = (lane < cnt) ? pay[base + lane] : SENT;
            __threadfence_block();
            int tr = (((cnt + 1) >> 1) + 3) & ~3;
            for (int t = 0; t < tr; t += 4) {
                float4 p0 = pb[2 * t + half];
                float4 p1 = pb[2 * t + 2 + half];
                float4 p2 = pb[2 * t + 4 + half];
                float4 p3 = pb[2 * t + 6 + half];
                float2 a0 = t2[((__float_as_int(p0.y) >> 12) & 0xFFF) + k];
                float2 a1 = t2[((__float_as_int(p1.y) >> 12) & 0xFFF) + k];
                float2 a2 = t2[((__float_as_int(p2.y) >> 12) & 0xFFF) + k];
                float2 a3 = t2[((__float_as_int(p3.y) >> 12) & 0xFFF) + k];
                acc0 = fmaf(a0.x, p0.x, acc0 + a0.y);
                acc1 = fmaf(a1.x, p1.x, acc1 + a1.y);
                acc2 = fmaf(a2.x, p2.x, acc2 + a2.y);
                acc3 = fmaf(a3.x, p3.x, acc3 + a3.y);
            }
            __threadfence_block();
        }
    } else {
        const float4* t4 = tabv;
        const int comp = k & 1, j = k >> 1;
        for (int base = beg; base < end; base += 64) {
            int cnt = min(end - base, 64);
            pb[lane] = (lane < cnt) ? pay[base + lane] : SENT;
            __threadfence_block();
            int tr = (((cnt + 1) >> 1) + 3) & ~3;
            for (int t = 0; t < tr; t += 4) {
                float4 p0 = pb[2 * t + half];
                float4 p1 = pb[2 * t + 2 + half];
                float4 p2 = pb[2 * t + 4 + half];
                float4 p3 = pb[2 * t + 6 + half];
                float4 c0 = t4[(__float_as_int(p0.y) & 0xFFF) + j];
                float4 c1 = t4[(__float_as_int(p1.y) & 0xFFF) + j];
                float4 c2 = t4[(__float_as_int(p2.y) & 0xFFF) + j];
                float4 c3 = t4[(__float_as_int(p3.y) & 0xFFF) + j];
                float m00 = fmaf(c0.x, p0.x, c0.y), m01 = fmaf(c0.z, p0.x, c0.w);
                float m10 = fmaf(c1.x, p1.x, c1.y), m11 = fmaf(c1.z, p1.x, c1.w);
                float m20 = fmaf(c2.x, p2.x, c2.y), m21 = fmaf(c2.z, p2.x, c2.w);
                float m30 = fmaf(c3.x, p3.x, c3.y), m31 = fmaf(c3.z, p3.x, c3.w);
                // even k: m0*c + m1*s ; odd k: m1*c - m0*s  (u,w per-lane selects)
                float u0 = comp ? -p0.w : p0.z, w0 = comp ? p0.z : p0.w;
                float u1 = comp ? -p1.w : p1.z, w1 = comp ? p1.z : p1.w;
                float u2 = comp ? -p2.w : p2.z, w2 = comp ? p2.z : p2.w;
                float u3 = comp ? -p3.w : p3.z, w3 = comp ? p3.z : p3.w;
                acc0 = fmaf(m00, u0, fmaf(m01, w0, acc0));
                acc1 = fmaf(m10, u1, fmaf(m11, w1, acc1));
                acc2 = fmaf(m20, u2, fmaf(m21, w2, acc2));
                acc3 = fmaf(m30, u3, fmaf(m31, w3, acc3));
            }
            __threadfence_block();
        }
    }

    float acc = (acc0 + acc1) + (acc2 + acc3);
    acc += __shfl_xor(acc, 32, 64);
    if (half == 0) {
        float* dst = out + (mode ? (size_t)N * 32 : 0) + (size_t)node * 32 + k;
        *dst = acc;
    }
}

extern "C" void kernel_launch(void* const* d_in, const int* in_sizes, int n_in,
                              void* d_out, int out_size, void* d_ws, size_t ws_size,
                              hipStream_t stream) {
    const float* v      = (const float*)d_in[0];
    const float* rot    = (const float*)d_in[1];
    const int*   ei     = (const int*)d_in[2];
    const float* msg_w1 = (const float*)d_in[3];
    const float* msg_b1 = (const float*)d_in[4];
    const float* msg_w2 = (const float*)d_in[5];
    const float* msg_b2 = (const float*)d_in[6];
    const float* sc_w1  = (const float*)d_in[7];
    const float* sc_b1  = (const float*)d_in[8];
    const float* sc_w2  = (const float*)d_in[9];
    const float* sc_b2  = (const float*)d_in[10];

    const int E = in_sizes[0] / 2;    // v is [E,2]
    const int N = out_size / 64;      // out = N*32 scalars + N*32 rot floats
    const int NBK = (N + NPB - 1) >> NPB_LOG;   // 782 for N=100000

    float* ws  = (float*)d_ws;
    float* out = (float*)d_out;

    int*    gbh  = (int*)(ws + WS_GBH);
    int*    gbo  = (int*)(ws + WS_GBO);
    int*    gcur = (int*)(ws + WS_GCUR);
    int*    offs = (int*)(ws + WS_OFFS);
    float4* pay  = (float4*)(ws + WS_PAY);
    size_t  pay2_req = ((size_t)WS_PAY + 8 * (size_t)E) * sizeof(float);
    float4* pay2 = (ws_size >= pay2_req) ? (float4*)(ws + WS_PAY + 4 * (size_t)E)
                                         : pay;   // in-place (fast path safe)

    build_breakpoints<<<1, 192, 0, stream>>>(msg_w1, msg_b1, sc_w1, sc_b1, ws);
    build_tables<<<dim3(NROW, 2), NOUT, 0, stream>>>(
        msg_w1, msg_b1, msg_w2, msg_b2, sc_w1, sc_b1, sc_w2, sc_b2, ws);

    hipMemsetAsync(gbh, 0, MAXBK * sizeof(int), stream);
    bucket_hist<<<256, 256, 0, stream>>>(ei + E, gbh, E, NBK);
    scan_buckets<<<1, 1024, 0, stream>>>(gbh, gbo, gcur, NBK);
    bucket_scatter<<<(E + EPB - 1) / EPB, 256, 0, stream>>>(
        v, rot, ei + E, ws, gcur, pay, E, NBK);
    bucket_finalize<<<NBK, 256, 0, stream>>>(pay, pay2, gbh, gbo, offs,
                                             N, NBK, E);
    gather_kernel<<<dim3((N + 3) / 4, 2), 256, 0, stream>>>(pay2, offs, ws, out, N);
}

// Round 8
// 163.932 us; speedup vs baseline: 1.3963x; 1.3963x over previous
//
#include <hip/hip_runtime.h>

#define H     96    // hidden width of both MLPs
#define NOUT  32    // outputs of both MLPs
#define NSEG  97    // H+1 piecewise-linear segments
#define TPAD  128   // breakpoint array padded to pow2 for branchless search
#define TABQ  1552  // float4 per table (97*16)

#define NPB_LOG 7
#define NPB     128   // nodes per bucket
#define MAXBK   800   // max buckets (N <= 102400)
#define EPB     8192  // edges per bucket_scatter block
#define CAP     3072  // max bucket size for fast path (mean 2048, +22 sigma)
#define NP      3     // CAP / 1024 payloads staged per thread

// ---- d_ws float-index layout -------------------------------------------
#define WS_TS_MSG   0          // float[128] sorted breakpoints (+inf pad)
#define WS_TS_SC    128        // float[128]
#define WS_ACS      256        // float2[97][32]  scalar (A, C+b2) [s][k]
#define WS_ACM      6464       // float4[97][16]  msg (A0,C0,A1,C1) [s][j]
#define WS_RANK     12672      // int[192]
#define WS_GBH      16384      // int[800]  bucket sizes
#define WS_GBO      17184      // int[800]  bucket offsets (excl scan)
#define WS_GCUR     17984      // int[800]  bucket cursors
#define WS_PAY      118788     // float4[E] bucket-grouped payloads

// ---------------------------------------------------------------------------
// P1: breakpoints t_j = -b1_j/w1_j, rank-sort, store sorted(+inf padded)+ranks
// ---------------------------------------------------------------------------
__global__ void build_breakpoints(const float* __restrict__ msg_w1,
                                  const float* __restrict__ msg_b1,
                                  const float* __restrict__ sc_w1,
                                  const float* __restrict__ sc_b1,
                                  float* __restrict__ ws) {
    __shared__ float t[2][H];
    const int tid = threadIdx.x;        // 192 threads
    const int mlp = tid / H;
    const int j   = tid % H;
    if (tid < 2 * H) {
        const float* w1 = mlp ? sc_w1 : msg_w1;
        const float* b1 = mlp ? sc_b1 : msg_b1;
        float w = w1[j], b = b1[j];
        t[mlp][j] = (w == 0.0f) ? __builtin_inff() : (-b / w);
    }
    __syncthreads();
    if (tid < 2 * H) {
        float tj = t[mlp][j];
        int r = 0;
        for (int i = 0; i < H; ++i) {
            float ti = t[mlp][i];
            r += (ti < tj) || (ti == tj && i < j);
        }
        float* ts = ws + (mlp ? WS_TS_SC : WS_TS_MSG);
        ts[r] = tj;
        ((int*)(ws + WS_RANK))[mlp * H + j] = r;
    }
    if (tid < 2 * (TPAD - H)) {
        int m2 = tid / (TPAD - H);
        int p  = tid % (TPAD - H);
        ws[m2 * TPAD + H + p] = __builtin_inff();
    }
}

// ---------------------------------------------------------------------------
// P2: per (segment, mlp): A,C with mlp(x) = A*x + C on that segment.
// sc  -> ws[WS_ACS + 2*(s*32+k)]           (A, C+b2)   [s][k] float2
// msg -> ws[WS_ACM + 4*(s*16+j) + 2*comp]  (A, C+b2)   [s][j] float4
// ---------------------------------------------------------------------------
__global__ void build_tables(const float* __restrict__ msg_w1,
                             const float* __restrict__ msg_b1,
                             const float* __restrict__ msg_w2,
                             const float* __restrict__ msg_b2,
                             const float* __restrict__ sc_w1,
                             const float* __restrict__ sc_b1,
                             const float* __restrict__ sc_w2,
                             const float* __restrict__ sc_b2,
                             float* __restrict__ ws) {
    const int s   = blockIdx.x;   // 0..96
    const int mlp = blockIdx.y;   // 0 = msg, 1 = sc
    const int k   = threadIdx.x;  // 0..31
    const float* w1 = mlp ? sc_w1 : msg_w1;
    const float* b1 = mlp ? sc_b1 : msg_b1;
    const float* w2 = mlp ? sc_w2 : msg_w2;
    const float* b2 = mlp ? sc_b2 : msg_b2;
    const int* rank = (const int*)(ws + WS_RANK) + mlp * H;
    float A = 0.0f, C = 0.0f;
    for (int j = 0; j < H; ++j) {
        float w = w1[j], b = b1[j];
        int   r = rank[j];
        bool active = (w > 0.0f) ? (r < s)
                    : (w < 0.0f) ? (r >= s)
                                 : (b > 0.0f);
        if (active) {
            float wk = w2[j * NOUT + k];
            A = fmaf(w, wk, A);
            C = fmaf(b, wk, C);
        }
    }
    C += b2[k];
    if (mlp) {
        float* dst = ws + WS_ACS + 2 * (s * 32 + k);
        dst[0] = A; dst[1] = C;
    } else {
        float* dst = ws + WS_ACM + 4 * (s * 16 + (k >> 1)) + 2 * (k & 1);
        dst[0] = A; dst[1] = C;
    }
}

// ---------------------------------------------------------------------------
// K1: bucket histogram (LDS-privatized)
// ---------------------------------------------------------------------------
__global__ __launch_bounds__(256) void bucket_hist(
    const int* __restrict__ col, int* __restrict__ gbh, int E, int NBK)
{
    __shared__ int lcnt[MAXBK];
    for (int i = threadIdx.x; i < MAXBK; i += 256) lcnt[i] = 0;
    __syncthreads();
    for (int e = blockIdx.x * 256 + threadIdx.x; e < E; e += gridDim.x * 256)
        atomicAdd(&lcnt[col[e] >> NPB_LOG], 1);
    __syncthreads();
    for (int i = threadIdx.x; i < NBK; i += 256)
        if (lcnt[i]) atomicAdd(&gbh[i], lcnt[i]);
}

// ---------------------------------------------------------------------------
// K2: exclusive scan of bucket sizes -> gbo, gcur (one block, 1024 threads)
// ---------------------------------------------------------------------------
__global__ void scan_buckets(const int* __restrict__ gbh,
                             int* __restrict__ gbo, int* __restrict__ gcur,
                             int NBK) {
    __shared__ int sh[1024];
    int t = threadIdx.x;
    int v = (t < NBK) ? gbh[t] : 0;
    sh[t] = v;
    __syncthreads();
    for (int off = 1; off < 1024; off <<= 1) {
        int u = (t >= off) ? sh[t - off] : 0;
        __syncthreads();
        sh[t] += u;
        __syncthreads();
    }
    if (t < NBK) { gbo[t] = sh[t] - v; gcur[t] = sh[t] - v; }
}

// ---------------------------------------------------------------------------
// K3: bucket scatter. payload = {x, sm | ss<<8 | (col&127)<<16, c, s}
// ---------------------------------------------------------------------------
__global__ __launch_bounds__(256) void bucket_scatter(
    const float* __restrict__ v, const float* __restrict__ rot,
    const int* __restrict__ col, const float* __restrict__ ws,
    int* __restrict__ gcur, float4* __restrict__ pay, int E, int NBK)
{
    __shared__ float ts_m[TPAD], ts_s[TPAD];
    __shared__ int lcnt[MAXBK], lbase[MAXBK];
    for (int i = threadIdx.x; i < 2 * TPAD; i += 256) {
        float val = ws[i];
        if (i < TPAD) ts_m[i] = val; else ts_s[i - TPAD] = val;
    }
    for (int i = threadIdx.x; i < MAXBK; i += 256) lcnt[i] = 0;
    __syncthreads();
    const int e0 = blockIdx.x * EPB;
    const int e1 = min(e0 + EPB, E);
    for (int e = e0 + threadIdx.x; e < e1; e += 256)
        atomicAdd(&lcnt[col[e] >> NPB_LOG], 1);
    __syncthreads();
    for (int b = threadIdx.x; b < NBK; b += 256) {
        int c = lcnt[b];
        lbase[b] = c ? atomicAdd(&gcur[b], c) : 0;
        lcnt[b] = 0;                       // reuse as cursor
    }
    __syncthreads();
    for (int e = e0 + threadIdx.x; e < e1; e += 256) {
        int    c  = col[e];
        float2 vv = *(const float2*)(v + 2 * (size_t)e);
        float  x  = sqrtf(vv.x * vv.x + vv.y * vv.y);
        float4 r  = *(const float4*)(rot + 4 * (size_t)e);
        int sm = 0;
        #pragma unroll
        for (int st = 64; st > 0; st >>= 1) if (ts_m[sm + st - 1] < x) sm += st;
        int ss = 0;
        #pragma unroll
        for (int st = 64; st > 0; st >>= 1) if (ts_s[ss + st - 1] < x) ss += st;
        int b   = c >> NPB_LOG;
        int pos = lbase[b] + atomicAdd(&lcnt[b], 1);
        pay[pos] = make_float4(x,
            __int_as_float(sm | (ss << 8) | ((c & (NPB - 1)) << 16)),
            r.x, r.z);
    }
}

// ---------------------------------------------------------------------------
// K4+gather fused: block = bucket (128 nodes), 1024 threads = 16 waves.
// Phase A: reorder bucket payloads into LDS buf (node-sorted, CSR in LDS).
// Phase B: 256 node x mode tasks interleaved across waves; R6-proven inner
// loop (wave = node-task, 32 outputs x 2 edge-slots, 2 acc chains, guards).
// LDS: 2 x 24832 (tables) + 49280 (buf) + 2 KB ctrl ~= 100 KB -> 1 block/CU,
// 16 waves/CU (same wave count as R6's gather at 51% occ).
// ---------------------------------------------------------------------------
__global__ __launch_bounds__(1024) void bucket_gather(
    const float4* __restrict__ pay, const int* __restrict__ gbh,
    const int* __restrict__ gbo, const float* __restrict__ ws,
    float* __restrict__ out, int N)
{
    __shared__ float4 tabS[TABQ];        // scalar table, viewed as float2[3104]
    __shared__ float4 tabM[TABQ];        // msg table
    __shared__ float4 buf[CAP + 8];      // node-sorted payloads (+pad)
    __shared__ int s_cnt[NPB], s_scan[NPB], s_loff[NPB], s_cur[NPB];

    const int tid = threadIdx.x;
    const int b   = blockIdx.x;
    const int lo  = b << NPB_LOG;
    const int nn  = min(NPB, N - lo);
    const int bbeg = gbo[b];
    const int bsz  = gbh[b];

    {   // table load + buf zero-init (pk=0 -> safe table row 0 when guarded)
        const float4* srcS = (const float4*)(ws + WS_ACS);
        const float4* srcM = (const float4*)(ws + WS_ACM);
        for (int i = tid; i < TABQ; i += 1024) { tabS[i] = srcS[i]; tabM[i] = srcM[i]; }
        for (int i = tid; i < CAP + 8; i += 1024) buf[i] = make_float4(0.f, 0.f, 0.f, 0.f);
        if (tid < NPB) s_cnt[tid] = 0;
    }
    __syncthreads();

    if (bsz <= CAP) {
        // ---- Phase A: stage -> count -> scan -> reorder into buf ----
        float4 p[NP];
        int    loc[NP];
        #pragma unroll
        for (int i = 0; i < NP; ++i) {
            int idx = i * 1024 + tid;
            loc[i] = -1;
            if (idx < bsz) {
                p[i] = pay[bbeg + idx];
                loc[i] = (__float_as_int(p[i].y) >> 16) & 127;
                atomicAdd(&s_cnt[loc[i]], 1);
            }
        }
        __syncthreads();
        if (tid < NPB) s_scan[tid] = s_cnt[tid];
        __syncthreads();
        for (int off = 1; off < NPB; off <<= 1) {
            int u = (tid < NPB && tid >= off) ? s_scan[tid - off] : 0;
            __syncthreads();
            if (tid < NPB) s_scan[tid] += u;
            __syncthreads();
        }
        if (tid < NPB) {
            s_loff[tid] = s_scan[tid] - s_cnt[tid];
            s_cur[tid]  = s_scan[tid] - s_cnt[tid];
        }
        __syncthreads();
        #pragma unroll
        for (int i = 0; i < NP; ++i) {
            if (loc[i] >= 0) {
                int pos = atomicAdd(&s_cur[loc[i]], 1);
                float4 q = p[i];
                q.y = __int_as_float(__float_as_int(q.y) & 0xFFFF);
                buf[pos] = q;
            }
        }
        __syncthreads();

        // ---- Phase B: 256 tasks (node x mode) over 16 waves, interleaved ----
        const int wv   = tid >> 6;
        const int lane = tid & 63;
        const int k    = lane & 31;
        const int half = lane >> 5;
        const float2* t2 = (const float2*)tabS;
        const int jj = k >> 1, comp = k & 1;

        for (int i = 0; i < 16; ++i) {
            int task = wv + (i << 4);
            int mode = task >> 7;
            int node = task & 127;
            if (node >= nn) continue;
            int beg = s_loff[node];
            int cnt = s_cnt[node];
            float acc = 0.f, acc2 = 0.f;
            int tmax = (cnt + 1) >> 1;
            if (mode == 0) {
                int t = 0;
                for (; t + 2 <= tmax; t += 2) {
                    int e0 = 2 * t + half, e1 = e0 + 2;
                    float4 p0 = buf[beg + e0];
                    float4 p1 = buf[beg + e1];
                    float2 a0 = t2[(__float_as_int(p0.y) >> 8) * 32 + k];
                    float2 a1 = t2[(__float_as_int(p1.y) >> 8) * 32 + k];
                    float v0 = fmaf(a0.x, p0.x, a0.y);
                    float v1 = fmaf(a1.x, p1.x, a1.y);
                    acc  += (e0 < cnt) ? v0 : 0.f;
                    acc2 += (e1 < cnt) ? v1 : 0.f;
                }
                if (t < tmax) {
                    int e0 = 2 * t + half;
                    float4 p0 = buf[beg + e0];
                    float2 a0 = t2[(__float_as_int(p0.y) >> 8) * 32 + k];
                    float v0 = fmaf(a0.x, p0.x, a0.y);
                    acc += (e0 < cnt) ? v0 : 0.f;
                }
            } else {
                int t = 0;
                for (; t + 2 <= tmax; t += 2) {
                    int e0 = 2 * t + half, e1 = e0 + 2;
                    float4 p0 = buf[beg + e0];
                    float4 p1 = buf[beg + e1];
                    float4 a0 = tabM[(__float_as_int(p0.y) & 255) * 16 + jj];
                    float4 a1 = tabM[(__float_as_int(p1.y) & 255) * 16 + jj];
                    float m00 = fmaf(a0.x, p0.x, a0.y);
                    float m01 = fmaf(a0.z, p0.x, a0.w);
                    float m10 = fmaf(a1.x, p1.x, a1.y);
                    float m11 = fmaf(a1.z, p1.x, a1.w);
                    float v0 = comp ? fmaf(m01, p0.z, -(m00 * p0.w))
                                    : fmaf(m00, p0.z, m01 * p0.w);
                    float v1 = comp ? fmaf(m11, p1.z, -(m10 * p1.w))
                                    : fmaf(m10, p1.z, m11 * p1.w);
                    acc  += (e0 < cnt) ? v0 : 0.f;
                    acc2 += (e1 < cnt) ? v1 : 0.f;
                }
                if (t < tmax) {
                    int e0 = 2 * t + half;
                    float4 p0 = buf[beg + e0];
                    float4 a0 = tabM[(__float_as_int(p0.y) & 255) * 16 + jj];
                    float m00 = fmaf(a0.x, p0.x, a0.y);
                    float m01 = fmaf(a0.z, p0.x, a0.w);
                    float v0 = comp ? fmaf(m01, p0.z, -(m00 * p0.w))
                                    : fmaf(m00, p0.z, m01 * p0.w);
                    acc += (e0 < cnt) ? v0 : 0.f;
                }
            }
            acc += acc2;
            acc += __shfl_xor(acc, 32, 64);
            if (half == 0) {
                float* dst = out + (mode ? (size_t)N * 32 : 0)
                           + (size_t)(lo + node) * 32 + k;
                *dst = acc;
            }
        }
    } else {
        // ---- cold path (bsz > CAP, statistically unreachable): LDS accum ----
        float* accum = (float*)buf;   // [128][64]
        for (int i = tid; i < NPB * 64; i += 1024) accum[i] = 0.f;
        __syncthreads();
        const float2* t2 = (const float2*)tabS;
        for (int idx = tid; idx < bsz; idx += 1024) {
            float4 q = pay[bbeg + idx];
            int pk = __float_as_int(q.y);
            int node = (pk >> 16) & 127;
            int sm = pk & 255, ss = (pk >> 8) & 255;
            float x = q.x, c = q.z, s = q.w;
            float* an = accum + node * 64;
            for (int kk = 0; kk < 32; ++kk) {
                float2 a = t2[ss * 32 + kk];
                atomicAdd(an + kk, fmaf(a.x, x, a.y));
            }
            for (int j2 = 0; j2 < 16; ++j2) {
                float4 a = tabM[sm * 16 + j2];
                float m0 = fmaf(a.x, x, a.y);
                float m1 = fmaf(a.z, x, a.w);
                atomicAdd(an + 32 + 2 * j2,     fmaf(m0, c, m1 * s));
                atomicAdd(an + 32 + 2 * j2 + 1, fmaf(m1, c, -(m0 * s)));
            }
        }
        __syncthreads();
        for (int i = tid; i < nn * 64; i += 1024) {
            int node = i >> 6, cc = i & 63;
            float* dst = out + ((cc < 32) ? 0 : (size_t)N * 32)
                       + (size_t)(lo + node) * 32 + (cc & 31);
            *dst = accum[node * 64 + cc];
        }
    }
}

extern "C" void kernel_launch(void* const* d_in, const int* in_sizes, int n_in,
                              void* d_out, int out_size, void* d_ws, size_t ws_size,
                              hipStream_t stream) {
    const float* v      = (const float*)d_in[0];
    const float* rot    = (const float*)d_in[1];
    const int*   ei     = (const int*)d_in[2];
    const float* msg_w1 = (const float*)d_in[3];
    const float* msg_b1 = (const float*)d_in[4];
    const float* msg_w2 = (const float*)d_in[5];
    const float* msg_b2 = (const float*)d_in[6];
    const float* sc_w1  = (const float*)d_in[7];
    const float* sc_b1  = (const float*)d_in[8];
    const float* sc_w2  = (const float*)d_in[9];
    const float* sc_b2  = (const float*)d_in[10];

    const int E = in_sizes[0] / 2;    // v is [E,2]
    const int N = out_size / 64;      // out = N*32 scalars + N*32 rot floats
    const int NBK = (N + NPB - 1) >> NPB_LOG;   // 782 for N=100000

    float* ws  = (float*)d_ws;
    float* out = (float*)d_out;

    int*    gbh  = (int*)(ws + WS_GBH);
    int*    gbo  = (int*)(ws + WS_GBO);
    int*    gcur = (int*)(ws + WS_GCUR);
    float4* pay  = (float4*)(ws + WS_PAY);

    build_breakpoints<<<1, 192, 0, stream>>>(msg_w1, msg_b1, sc_w1, sc_b1, ws);
    build_tables<<<dim3(NSEG, 2), NOUT, 0, stream>>>(
        msg_w1, msg_b1, msg_w2, msg_b2, sc_w1, sc_b1, sc_w2, sc_b2, ws);

    hipMemsetAsync(gbh, 0, MAXBK * sizeof(int), stream);
    bucket_hist<<<256, 256, 0, stream>>>(ei + E, gbh, E, NBK);
    scan_buckets<<<1, 1024, 0, stream>>>(gbh, gbo, gcur, NBK);
    bucket_scatter<<<(E + EPB - 1) / EPB, 256, 0, stream>>>(
        v, rot, ei + E, ws, gcur, pay, E, NBK);
    bucket_gather<<<NBK, 1024, 0, stream>>>(pay, gbh, gbo, ws, out, N);
}

// Round 9
// 139.329 us; speedup vs baseline: 1.6428x; 1.1766x over previous
//
#include <hip/hip_runtime.h>

#define H     96    // hidden width of both MLPs
#define NOUT  32    // outputs of both MLPs
#define NSEG  97    // H+1 piecewise-linear segments
#define TPAD  128   // breakpoint array padded to pow2 for branchless search
#define TABQ  1552  // float4 per table (97*16)

#define NPB_LOG 6
#define NPB     64    // nodes per bucket
#define MAXBK   1600  // max buckets (N <= 102400)
#define EPB     8192  // edges per bucket_scatter block
#define CAP     1536  // max bucket size for fast path (mean 1024, +16 sigma)
#define NP      2     // CAP / 1024 rounded up: payloads staged per thread

// ---- d_ws float-index layout -------------------------------------------
#define WS_TS_MSG   0          // float[128] sorted breakpoints (+inf pad)
#define WS_TS_SC    128        // float[128]
#define WS_ACS      256        // float2[97][32]  scalar (A, C+b2) [s][k]
#define WS_ACM      6464       // float4[97][16]  msg (A0,C0,A1,C1) [s][j]
#define WS_RANK     12672      // int[192]
#define WS_GBH      16384      // int[1600]  bucket sizes
#define WS_GBO      18048      // int[1600]  bucket offsets (excl scan)
#define WS_GCUR     19712      // int[1600]  bucket cursors
#define WS_PAY      21376      // float4[E]  bucket-grouped payloads

// ---------------------------------------------------------------------------
// P1: breakpoints t_j = -b1_j/w1_j, rank-sort, store sorted(+inf padded)+ranks
// ---------------------------------------------------------------------------
__global__ void build_breakpoints(const float* __restrict__ msg_w1,
                                  const float* __restrict__ msg_b1,
                                  const float* __restrict__ sc_w1,
                                  const float* __restrict__ sc_b1,
                                  float* __restrict__ ws) {
    __shared__ float t[2][H];
    const int tid = threadIdx.x;        // 192 threads
    const int mlp = tid / H;
    const int j   = tid % H;
    if (tid < 2 * H) {
        const float* w1 = mlp ? sc_w1 : msg_w1;
        const float* b1 = mlp ? sc_b1 : msg_b1;
        float w = w1[j], b = b1[j];
        t[mlp][j] = (w == 0.0f) ? __builtin_inff() : (-b / w);
    }
    __syncthreads();
    if (tid < 2 * H) {
        float tj = t[mlp][j];
        int r = 0;
        for (int i = 0; i < H; ++i) {
            float ti = t[mlp][i];
            r += (ti < tj) || (ti == tj && i < j);
        }
        float* ts = ws + (mlp ? WS_TS_SC : WS_TS_MSG);
        ts[r] = tj;
        ((int*)(ws + WS_RANK))[mlp * H + j] = r;
    }
    if (tid < 2 * (TPAD - H)) {
        int m2 = tid / (TPAD - H);
        int p  = tid % (TPAD - H);
        ws[m2 * TPAD + H + p] = __builtin_inff();
    }
}

// ---------------------------------------------------------------------------
// P2: per (segment, mlp): A,C with mlp(x) = A*x + C on that segment.
// ---------------------------------------------------------------------------
__global__ void build_tables(const float* __restrict__ msg_w1,
                             const float* __restrict__ msg_b1,
                             const float* __restrict__ msg_w2,
                             const float* __restrict__ msg_b2,
                             const float* __restrict__ sc_w1,
                             const float* __restrict__ sc_b1,
                             const float* __restrict__ sc_w2,
                             const float* __restrict__ sc_b2,
                             float* __restrict__ ws) {
    const int s   = blockIdx.x;   // 0..96
    const int mlp = blockIdx.y;   // 0 = msg, 1 = sc
    const int k   = threadIdx.x;  // 0..31
    const float* w1 = mlp ? sc_w1 : msg_w1;
    const float* b1 = mlp ? sc_b1 : msg_b1;
    const float* w2 = mlp ? sc_w2 : msg_w2;
    const float* b2 = mlp ? sc_b2 : msg_b2;
    const int* rank = (const int*)(ws + WS_RANK) + mlp * H;
    float A = 0.0f, C = 0.0f;
    for (int j = 0; j < H; ++j) {
        float w = w1[j], b = b1[j];
        int   r = rank[j];
        bool active = (w > 0.0f) ? (r < s)
                    : (w < 0.0f) ? (r >= s)
                                 : (b > 0.0f);
        if (active) {
            float wk = w2[j * NOUT + k];
            A = fmaf(w, wk, A);
            C = fmaf(b, wk, C);
        }
    }
    C += b2[k];
    if (mlp) {
        float* dst = ws + WS_ACS + 2 * (s * 32 + k);
        dst[0] = A; dst[1] = C;
    } else {
        float* dst = ws + WS_ACM + 4 * (s * 16 + (k >> 1)) + 2 * (k & 1);
        dst[0] = A; dst[1] = C;
    }
}

// ---------------------------------------------------------------------------
// K1: bucket histogram (LDS-privatized)
// ---------------------------------------------------------------------------
__global__ __launch_bounds__(256) void bucket_hist(
    const int* __restrict__ col, int* __restrict__ gbh, int E, int NBK)
{
    __shared__ int lcnt[MAXBK];
    for (int i = threadIdx.x; i < MAXBK; i += 256) lcnt[i] = 0;
    __syncthreads();
    for (int e = blockIdx.x * 256 + threadIdx.x; e < E; e += gridDim.x * 256)
        atomicAdd(&lcnt[col[e] >> NPB_LOG], 1);
    __syncthreads();
    for (int i = threadIdx.x; i < NBK; i += 256)
        if (lcnt[i]) atomicAdd(&gbh[i], lcnt[i]);
}

// ---------------------------------------------------------------------------
// K2: exclusive scan of bucket sizes (2 elems/thread -> up to 2048 buckets)
// ---------------------------------------------------------------------------
__global__ void scan_buckets(const int* __restrict__ gbh,
                             int* __restrict__ gbo, int* __restrict__ gcur,
                             int NBK) {
    __shared__ int sh[1024];
    int t = threadIdx.x;
    int i0 = 2 * t, i1 = 2 * t + 1;
    int a = (i0 < NBK) ? gbh[i0] : 0;
    int b = (i1 < NBK) ? gbh[i1] : 0;
    int s = a + b;
    sh[t] = s;
    __syncthreads();
    for (int off = 1; off < 1024; off <<= 1) {
        int u = (t >= off) ? sh[t - off] : 0;
        __syncthreads();
        sh[t] += u;
        __syncthreads();
    }
    int excl = sh[t] - s;
    if (i0 < NBK) { gbo[i0] = excl;     gcur[i0] = excl; }
    if (i1 < NBK) { gbo[i1] = excl + a; gcur[i1] = excl + a; }
}

// ---------------------------------------------------------------------------
// K3: bucket scatter. payload = {x, sm | ss<<8 | (col&63)<<16, c, s}
// ---------------------------------------------------------------------------
__global__ __launch_bounds__(256) void bucket_scatter(
    const float* __restrict__ v, const float* __restrict__ rot,
    const int* __restrict__ col, const float* __restrict__ ws,
    int* __restrict__ gcur, float4* __restrict__ pay, int E, int NBK)
{
    __shared__ float ts_m[TPAD], ts_s[TPAD];
    __shared__ int lcnt[MAXBK], lbase[MAXBK];
    for (int i = threadIdx.x; i < 2 * TPAD; i += 256) {
        float val = ws[i];
        if (i < TPAD) ts_m[i] = val; else ts_s[i - TPAD] = val;
    }
    for (int i = threadIdx.x; i < MAXBK; i += 256) lcnt[i] = 0;
    __syncthreads();
    const int e0 = blockIdx.x * EPB;
    const int e1 = min(e0 + EPB, E);
    for (int e = e0 + threadIdx.x; e < e1; e += 256)
        atomicAdd(&lcnt[col[e] >> NPB_LOG], 1);
    __syncthreads();
    for (int b = threadIdx.x; b < NBK; b += 256) {
        int c = lcnt[b];
        lbase[b] = c ? atomicAdd(&gcur[b], c) : 0;
        lcnt[b] = 0;                       // reuse as cursor
    }
    __syncthreads();
    for (int e = e0 + threadIdx.x; e < e1; e += 256) {
        int    c  = col[e];
        float2 vv = *(const float2*)(v + 2 * (size_t)e);
        float  x  = sqrtf(vv.x * vv.x + vv.y * vv.y);
        float4 r  = *(const float4*)(rot + 4 * (size_t)e);
        int sm = 0;
        #pragma unroll
        for (int st = 64; st > 0; st >>= 1) if (ts_m[sm + st - 1] < x) sm += st;
        int ss = 0;
        #pragma unroll
        for (int st = 64; st > 0; st >>= 1) if (ts_s[ss + st - 1] < x) ss += st;
        int b   = c >> NPB_LOG;
        int pos = lbase[b] + atomicAdd(&lcnt[b], 1);
        pay[pos] = make_float4(x,
            __int_as_float(sm | (ss << 8) | ((c & (NPB - 1)) << 16)),
            r.x, r.z);
    }
}

// ---------------------------------------------------------------------------
// K4+gather fused: block = bucket (64 nodes), 1024 threads = 16 waves.
// Phase A: reorder bucket payloads into LDS buf (node-sorted, CSR in LDS).
// Phase B: 128 node x mode tasks over 16 waves; R6-proven inner loop.
// LDS: 2 x 24832 (tables) + 24704 (buf) + 1 KB ctrl = 75.4 KB -> 2 blocks/CU,
// 32 waves/CU (2x R8's occupancy).
// ---------------------------------------------------------------------------
__global__ __launch_bounds__(1024, 8) void bucket_gather(
    const float4* __restrict__ pay, const int* __restrict__ gbh,
    const int* __restrict__ gbo, const float* __restrict__ ws,
    float* __restrict__ out, int N)
{
    __shared__ float4 tabS[TABQ];        // scalar table, viewed as float2[3104]
    __shared__ float4 tabM[TABQ];        // msg table
    __shared__ float4 buf[CAP + 8];      // node-sorted payloads (+pad)
    __shared__ int s_cnt[NPB], s_scan[NPB], s_loff[NPB], s_cur[NPB];

    const int tid = threadIdx.x;
    const int b   = blockIdx.x;
    const int lo  = b << NPB_LOG;
    const int nn  = min(NPB, N - lo);
    const int bbeg = gbo[b];
    const int bsz  = gbh[b];

    {   // table load + buf zero-init (pk=0 -> safe table row 0 when guarded)
        const float4* srcS = (const float4*)(ws + WS_ACS);
        const float4* srcM = (const float4*)(ws + WS_ACM);
        for (int i = tid; i < TABQ; i += 1024) { tabS[i] = srcS[i]; tabM[i] = srcM[i]; }
        for (int i = tid; i < CAP + 8; i += 1024) buf[i] = make_float4(0.f, 0.f, 0.f, 0.f);
        if (tid < NPB) s_cnt[tid] = 0;
    }
    __syncthreads();

    if (bsz <= CAP) {
        // ---- Phase A: stage -> count -> scan -> reorder into buf ----
        float4 p[NP];
        int    loc[NP];
        #pragma unroll
        for (int i = 0; i < NP; ++i) {
            int idx = i * 1024 + tid;
            loc[i] = -1;
            if (idx < bsz) {
                p[i] = pay[bbeg + idx];
                loc[i] = (__float_as_int(p[i].y) >> 16) & (NPB - 1);
                atomicAdd(&s_cnt[loc[i]], 1);
            }
        }
        __syncthreads();
        if (tid < NPB) s_scan[tid] = s_cnt[tid];
        __syncthreads();
        for (int off = 1; off < NPB; off <<= 1) {
            int u = (tid < NPB && tid >= off) ? s_scan[tid - off] : 0;
            __syncthreads();
            if (tid < NPB) s_scan[tid] += u;
            __syncthreads();
        }
        if (tid < NPB) {
            s_loff[tid] = s_scan[tid] - s_cnt[tid];
            s_cur[tid]  = s_scan[tid] - s_cnt[tid];
        }
        __syncthreads();
        #pragma unroll
        for (int i = 0; i < NP; ++i) {
            if (loc[i] >= 0) {
                int pos = atomicAdd(&s_cur[loc[i]], 1);
                float4 q = p[i];
                q.y = __int_as_float(__float_as_int(q.y) & 0xFFFF);
                buf[pos] = q;
            }
        }
        __syncthreads();

        // ---- Phase B: 128 tasks (node x mode) over 16 waves ----
        const int wv   = tid >> 6;
        const int lane = tid & 63;
        const int k    = lane & 31;
        const int half = lane >> 5;
        const float2* t2 = (const float2*)tabS;
        const int jj = k >> 1, comp = k & 1;

        for (int i = 0; i < 8; ++i) {
            int task = wv + (i << 4);     // 0..127
            int mode = task >> NPB_LOG;
            int node = task & (NPB - 1);
            if (node >= nn) continue;
            int beg = s_loff[node];
            int cnt = s_cnt[node];
            float acc = 0.f, acc2 = 0.f;
            int tmax = (cnt + 1) >> 1;
            if (mode == 0) {
                int t = 0;
                for (; t + 2 <= tmax; t += 2) {
                    int e0 = 2 * t + half, e1 = e0 + 2;
                    float4 p0 = buf[beg + e0];
                    float4 p1 = buf[beg + e1];
                    float2 a0 = t2[(__float_as_int(p0.y) >> 8) * 32 + k];
                    float2 a1 = t2[(__float_as_int(p1.y) >> 8) * 32 + k];
                    float v0 = fmaf(a0.x, p0.x, a0.y);
                    float v1 = fmaf(a1.x, p1.x, a1.y);
                    acc  += (e0 < cnt) ? v0 : 0.f;
                    acc2 += (e1 < cnt) ? v1 : 0.f;
                }
                if (t < tmax) {
                    int e0 = 2 * t + half;
                    float4 p0 = buf[beg + e0];
                    float2 a0 = t2[(__float_as_int(p0.y) >> 8) * 32 + k];
                    float v0 = fmaf(a0.x, p0.x, a0.y);
                    acc += (e0 < cnt) ? v0 : 0.f;
                }
            } else {
                int t = 0;
                for (; t + 2 <= tmax; t += 2) {
                    int e0 = 2 * t + half, e1 = e0 + 2;
                    float4 p0 = buf[beg + e0];
                    float4 p1 = buf[beg + e1];
                    float4 a0 = tabM[(__float_as_int(p0.y) & 255) * 16 + jj];
                    float4 a1 = tabM[(__float_as_int(p1.y) & 255) * 16 + jj];
                    float m00 = fmaf(a0.x, p0.x, a0.y);
                    float m01 = fmaf(a0.z, p0.x, a0.w);
                    float m10 = fmaf(a1.x, p1.x, a1.y);
                    float m11 = fmaf(a1.z, p1.x, a1.w);
                    float v0 = comp ? fmaf(m01, p0.z, -(m00 * p0.w))
                                    : fmaf(m00, p0.z, m01 * p0.w);
                    float v1 = comp ? fmaf(m11, p1.z, -(m10 * p1.w))
                                    : fmaf(m10, p1.z, m11 * p1.w);
                    acc  += (e0 < cnt) ? v0 : 0.f;
                    acc2 += (e1 < cnt) ? v1 : 0.f;
                }
                if (t < tmax) {
                    int e0 = 2 * t + half;
                    float4 p0 = buf[beg + e0];
                    float4 a0 = tabM[(__float_as_int(p0.y) & 255) * 16 + jj];
                    float m00 = fmaf(a0.x, p0.x, a0.y);
                    float m01 = fmaf(a0.z, p0.x, a0.w);
                    float v0 = comp ? fmaf(m01, p0.z, -(m00 * p0.w))
                                    : fmaf(m00, p0.z, m01 * p0.w);
                    acc += (e0 < cnt) ? v0 : 0.f;
                }
            }
            acc += acc2;
            acc += __shfl_xor(acc, 32, 64);
            if (half == 0) {
                float* dst = out + (mode ? (size_t)N * 32 : 0)
                           + (size_t)(lo + node) * 32 + k;
                *dst = acc;
            }
        }
    } else {
        // ---- cold path (bsz > CAP, statistically unreachable): LDS accum ----
        float* accum = (float*)buf;   // [64][64]
        for (int i = tid; i < NPB * 64; i += 1024) accum[i] = 0.f;
        __syncthreads();
        const float2* t2 = (const float2*)tabS;
        for (int idx = tid; idx < bsz; idx += 1024) {
            float4 q = pay[bbeg + idx];
            int pk = __float_as_int(q.y);
            int node = (pk >> 16) & (NPB - 1);
            int sm = pk & 255, ss = (pk >> 8) & 255;
            float x = q.x, c = q.z, s = q.w;
            float* an = accum + node * 64;
            for (int kk = 0; kk < 32; ++kk) {
                float2 a = t2[ss * 32 + kk];
                atomicAdd(an + kk, fmaf(a.x, x, a.y));
            }
            for (int j2 = 0; j2 < 16; ++j2) {
                float4 a = tabM[sm * 16 + j2];
                float m0 = fmaf(a.x, x, a.y);
                float m1 = fmaf(a.z, x, a.w);
                atomicAdd(an + 32 + 2 * j2,     fmaf(m0, c, m1 * s));
                atomicAdd(an + 32 + 2 * j2 + 1, fmaf(m1, c, -(m0 * s)));
            }
        }
        __syncthreads();
        for (int i = tid; i < nn * 64; i += 1024) {
            int node = i >> 6, cc = i & 63;
            float* dst = out + ((cc < 32) ? 0 : (size_t)N * 32)
                       + (size_t)(lo + node) * 32 + (cc & 31);
            *dst = accum[node * 64 + cc];
        }
    }
}

extern "C" void kernel_launch(void* const* d_in, const int* in_sizes, int n_in,
                              void* d_out, int out_size, void* d_ws, size_t ws_size,
                              hipStream_t stream) {
    const float* v      = (const float*)d_in[0];
    const float* rot    = (const float*)d_in[1];
    const int*   ei     = (const int*)d_in[2];
    const float* msg_w1 = (const float*)d_in[3];
    const float* msg_b1 = (const float*)d_in[4];
    const float* msg_w2 = (const float*)d_in[5];
    const float* msg_b2 = (const float*)d_in[6];
    const float* sc_w1  = (const float*)d_in[7];
    const float* sc_b1  = (const float*)d_in[8];
    const float* sc_w2  = (const float*)d_in[9];
    const float* sc_b2  = (const float*)d_in[10];

    const int E = in_sizes[0] / 2;    // v is [E,2]
    const int N = out_size / 64;      // out = N*32 scalars + N*32 rot floats
    const int NBK = (N + NPB - 1) >> NPB_LOG;   // 1563 for N=100000

    float* ws  = (float*)d_ws;
    float* out = (float*)d_out;

    int*    gbh  = (int*)(ws + WS_GBH);
    int*    gbo  = (int*)(ws + WS_GBO);
    int*    gcur = (int*)(ws + WS_GCUR);
    float4* pay  = (float4*)(ws + WS_PAY);

    build_breakpoints<<<1, 192, 0, stream>>>(msg_w1, msg_b1, sc_w1, sc_b1, ws);
    build_tables<<<dim3(NSEG, 2), NOUT, 0, stream>>>(
        msg_w1, msg_b1, msg_w2, msg_b2, sc_w1, sc_b1, sc_w2, sc_b2, ws);

    hipMemsetAsync(gbh, 0, MAXBK * sizeof(int), stream);
    bucket_hist<<<256, 256, 0, stream>>>(ei + E, gbh, E, NBK);
    scan_buckets<<<1, 1024, 0, stream>>>(gbh, gbo, gcur, NBK);
    bucket_scatter<<<(E + EPB - 1) / EPB, 256, 0, stream>>>(
        v, rot, ei + E, ws, gcur, pay, E, NBK);
    bucket_gather<<<NBK, 1024, 0, stream>>>(pay, gbh, gbo, ws, out, N);
}